// Round 6
// baseline (572.065 us; speedup 1.0000x reference)
//
#include <hip/hip_runtime.h>
#include <hip/hip_bf16.h>
#include <cstdio>

#define N_NODES 100000
#define E_EDGES 3200000
#define N_GRAPH 512
#define HDIM 64
#define BN_EPS 1e-5f
#define NBUCKET ((N_NODES + 255) / 256)   // 391 buckets of 256 nodes
#define NCHUNK 256                        // edge chunks (radix partition)
#define CHUNK ((E_EDGES + NCHUNK - 1) / NCHUNK) // 12500 edges/chunk
#define SORT_CAP 12288                    // per-bucket LDS entries (mean 8192, max ~8600)

typedef _Float16 f16;
typedef _Float16 half4 __attribute__((ext_vector_type(4)));
typedef _Float16 half8 __attribute__((ext_vector_type(8)));

// ======== counter-free radix partition of edges by dst>>8 ========

__global__ __launch_bounds__(256) void hist_k(const int* __restrict__ dst,
                                              int* __restrict__ histT) {
    __shared__ int h[NBUCKET];
    int c = blockIdx.x, t = threadIdx.x;
    for (int i = t; i < NBUCKET; i += 256) h[i] = 0;
    __syncthreads();
    int e0 = c * CHUNK;
    int e1 = min(e0 + CHUNK, E_EDGES);
    for (int e = e0 + t; e < e1; e += 256)
        atomicAdd(&h[__builtin_nontemporal_load(dst + e) >> 8], 1);
    __syncthreads();
    for (int i = t; i < NBUCKET; i += 256) histT[i * NCHUNK + c] = h[i];
}

// bucket totals + exclusive scan; ALSO precomputes layer-1 affine m1c1[f]
__global__ void scanA_k(const int* __restrict__ histT, int* __restrict__ bucket_base,
                        const float* __restrict__ w1, const float* __restrict__ b1,
                        const float* __restrict__ bg1, const float* __restrict__ bb1,
                        const float* __restrict__ brm1, const float* __restrict__ brv1,
                        float2* __restrict__ m1c1) {
    __shared__ int sh[512];
    int t = threadIdx.x;
    if (t < HDIM) {  // layer-1 affine: relu(m*sfull + c) = post-BN feature
        float sc1 = bg1[t] * rsqrtf(brv1[t] + BN_EPS);
        m1c1[t] = make_float2(sc1 * w1[t], (b1[t] - brm1[t]) * sc1 + bb1[t]);
    }
    int sum = 0;
    if (t < NBUCKET) {
        const int* row = histT + t * NCHUNK;
        for (int c = 0; c < NCHUNK; c++) sum += row[c];
    }
    sh[t] = sum;
    __syncthreads();
    for (int off = 1; off < 512; off <<= 1) {
        int add = (t >= off) ? sh[t - off] : 0;
        __syncthreads();
        sh[t] += add;
        __syncthreads();
    }
    if (t < NBUCKET) bucket_base[t] = sh[t] - sum;
    if (t == 0) bucket_base[NBUCKET] = E_EDGES;
}

__global__ __launch_bounds__(NCHUNK) void scanB_k(const int* __restrict__ histT,
                                                  const int* __restrict__ bucket_base,
                                                  int* __restrict__ scannedT) {
    __shared__ int sh[NCHUNK];
    int b = blockIdx.x, t = threadIdx.x;
    int v = histT[b * NCHUNK + t];
    sh[t] = v;
    __syncthreads();
    for (int off = 1; off < NCHUNK; off <<= 1) {
        int add = (t >= off) ? sh[t - off] : 0;
        __syncthreads();
        sh[t] += add;
        __syncthreads();
    }
    scannedT[b * NCHUNK + t] = bucket_base[b] + sh[t] - v;
}

__global__ __launch_bounds__(256) void scatter_k(const int* __restrict__ src,
                                                 const int* __restrict__ dst,
                                                 const int* __restrict__ scannedT,
                                                 int* __restrict__ staging) {
    __shared__ int lcnt[NBUCKET];
    int c = blockIdx.x, t = threadIdx.x;
    for (int i = t; i < NBUCKET; i += 256) lcnt[i] = scannedT[i * NCHUNK + c];
    __syncthreads();
    int e0 = c * CHUNK;
    int e1 = min(e0 + CHUNK, E_EDGES);
    for (int e = e0 + t; e < e1; e += 256) {
        int v = __builtin_nontemporal_load(dst + e);
        int u = __builtin_nontemporal_load(src + e);
        int pos = atomicAdd(&lcnt[v >> 8], 1);       // LDS atomic
        staging[pos] = u | ((v & 255) << 17);        // 4B, ~128B runs per bucket
    }
}

// ======== per-bucket: degrees->ptr/dinv/xtil + grouped CSR sort (merged) ========

__global__ __launch_bounds__(256) void build_k(const int* __restrict__ staging,
                                               const int* __restrict__ bucket_base,
                                               const float* __restrict__ x,
                                               int* __restrict__ ptr,
                                               float* __restrict__ dinv,
                                               float* __restrict__ xtil,
                                               int* __restrict__ csr) {
    __shared__ int hn[256];
    __shared__ int sc[256];
    __shared__ int lcnt[256];
    __shared__ int lds_u[SORT_CAP];
    int t = threadIdx.x, b = blockIdx.x;
    int v0 = b << 8;
    int p0 = bucket_base[b], p1 = bucket_base[b + 1];
    int cnt = p1 - p0;
    hn[t] = 0;
    __syncthreads();
    for (int i = t; i < cnt; i += 256)
        atomicAdd(&hn[staging[p0 + i] >> 17], 1);
    __syncthreads();
    int my = hn[t];
    sc[t] = my;
    __syncthreads();
    for (int off = 1; off < 256; off <<= 1) {
        int add = (t >= off) ? sc[t - off] : 0;
        __syncthreads();
        sc[t] += add;
        __syncthreads();
    }
    int base = sc[t] - my;       // exclusive prefix within bucket
    hn[t] = base;                // hn now holds per-node bases
    lcnt[t] = 0;
    int v = v0 + t;
    if (v < N_NODES) {
        ptr[v] = p0 + base;
        float dv = rsqrtf((float)(my + 1));
        dinv[v] = dv;
        xtil[v] = dv * x[v];
    }
    if (b == NBUCKET - 1 && t == 0) ptr[N_NODES] = E_EDGES;
    __syncthreads();
    for (int i = t; i < cnt; i += 256) {
        int packed = staging[p0 + i];          // L2-hot second pass
        int u = packed & 0x1FFFF;
        int vl = packed >> 17;
        int r = atomicAdd(&lcnt[vl], 1);
        int pos = hn[vl] + r;
        if (pos < SORT_CAP) lds_u[pos] = u;
        else csr[p0 + pos] = u;                // overflow fallback (never at this scale)
    }
    __syncthreads();
    int lim = (cnt < SORT_CAP) ? cnt : SORT_CAP;
    for (int i = t; i < lim; i += 256) csr[p0 + i] = lds_u[i]; // coalesced
}

// ======== layer-1 scalar sum: pairs[v] = {sfull, dinv} (lane-parallel gather) ========

__global__ __launch_bounds__(256) void l1sum_k(const int* __restrict__ ptr,
                                               const int* __restrict__ csr,
                                               const float* __restrict__ dinv,
                                               const float* __restrict__ xtil,
                                               const float* __restrict__ x,
                                               float2* __restrict__ pairs) {
    int tid = threadIdx.x;
    int lane = tid & 63;
    int v = (blockIdx.x << 2) + (tid >> 6);
    if (v >= N_NODES) return;
    int e0 = ptr[v], e1 = ptr[v + 1];
    float a = 0.f;
    for (int e = e0 + lane; e < e1; e += 64)
        a += xtil[csr[e]];                    // 4B gather, 400KB L2-resident table
#pragma unroll
    for (int m = 1; m <= 32; m <<= 1) a += __shfl_xor(a, m);
    if (lane == 0) {
        float dv = dinv[v];
        pairs[v] = make_float2(dv * a + dv * dv * x[v], dv);
    }
}

// ======== Layer-2 aggregate: pairs gather + relu-reconstruct -> agg2 f32 rows ========
// x1til[u,f] = dinv_u * relu(m1[f]*sfull_u + c1[f]) reconstructed in-register.
// Octet o=lane>>3 = edge slot, s=lane&7 -> features s*8..s*8+7. No epilogue GEMM.

__global__ __launch_bounds__(256) void agg2_k(
    const float2* __restrict__ pairs, const float2* __restrict__ m1c1,
    const int* __restrict__ ptr, const int* __restrict__ csr,
    float* __restrict__ agg2) {
    int tid = threadIdx.x;
    int lane = tid & 63;
    int v = (blockIdx.x << 2) + (tid >> 6);
    if (v >= N_NODES) return;
    int o = lane >> 3, s = lane & 7;

    float m1[8], c1[8];
#pragma unroll
    for (int i = 0; i < 8; i++) {
        float2 mc = m1c1[s * 8 + i];          // contiguous 64B per octet
        m1[i] = mc.x; c1[i] = mc.y;
    }

    int e0 = ptr[v], e1 = ptr[v + 1];
    float2 pv = pairs[v];
    float acc[8];
    {
        float cf = (o == 0) ? pv.y : 0.f;     // self-loop, once
#pragma unroll
        for (int i = 0; i < 8; i++)
            acc[i] = cf * fmaxf(m1[i] * pv.x + c1[i], 0.f);
    }
    for (int e = e0; e < e1; e += 16) {
#pragma unroll
        for (int j = 0; j < 2; j++) {
            int ee = e + j * 8 + o;
            int eidx = (ee < e1) ? ee : (e1 - 1);  // clamp: same line
            int u = __builtin_nontemporal_load(csr + eidx);
            float2 p = pairs[u];                   // 8B gather, L2-resident
            float cf = (ee < e1) ? p.y : 0.f;
#pragma unroll
            for (int i = 0; i < 8; i++)
                acc[i] += cf * fmaxf(m1[i] * p.x + c1[i], 0.f);
        }
    }
#pragma unroll
    for (int i = 0; i < 8; i++) {
        acc[i] += __shfl_xor(acc[i], 8);
        acc[i] += __shfl_xor(acc[i], 16);
        acc[i] += __shfl_xor(acc[i], 32);
    }
    if (o == 0) {
        float4 lo = {acc[0], acc[1], acc[2], acc[3]};
        float4 hi = {acc[4], acc[5], acc[6], acc[7]};
        float4* out = (float4*)(agg2 + (size_t)v * HDIM + s * 8);
        out[0] = lo;
        out[1] = hi;
    }
}

// ======== dense transform: out = relu(dv*(agg@W)*sM + sC) [*dv if prescale] ========
// Thread per node, o[64] accumulators, W broadcast from LDS.

__global__ __launch_bounds__(256) void gemv_k(
    const float* __restrict__ agg, const float2* __restrict__ pairs,
    f16* __restrict__ xout,
    const float* __restrict__ W, const float* __restrict__ bias,
    const float* __restrict__ bg, const float* __restrict__ bb,
    const float* __restrict__ brm, const float* __restrict__ brv,
    int prescale) {
    __shared__ float wsh[HDIM * HDIM];
    __shared__ float sM[HDIM], sC[HDIM];
    int tid = threadIdx.x;
    for (int i = tid; i < HDIM * HDIM; i += 256) wsh[i] = W[i];
    if (tid < HDIM) {
        float sc = bg[tid] * rsqrtf(brv[tid] + BN_EPS);
        sM[tid] = sc;
        sC[tid] = (bias[tid] - brm[tid]) * sc + bb[tid];
    }
    __syncthreads();
    int v = blockIdx.x * 256 + tid;
    if (v >= N_NODES) return;

    float o[HDIM];
#pragma unroll
    for (int f = 0; f < HDIM; f++) o[f] = 0.f;

    const float4* a4 = (const float4*)(agg + (size_t)v * HDIM);
#pragma unroll 1
    for (int k4 = 0; k4 < 16; k4++) {
        float4 av = a4[k4];                       // 16B streaming read
#pragma unroll
        for (int kk = 0; kk < 4; kk++) {
            float a = (kk == 0) ? av.x : (kk == 1) ? av.y : (kk == 2) ? av.z : av.w;
            const float4* wrow = (const float4*)&wsh[(k4 * 4 + kk) * HDIM];
#pragma unroll
            for (int f4 = 0; f4 < 16; f4++) {
                float4 wv = wrow[f4];             // broadcast ds_read_b128
                o[f4 * 4 + 0] += a * wv.x;
                o[f4 * 4 + 1] += a * wv.y;
                o[f4 * 4 + 2] += a * wv.z;
                o[f4 * 4 + 3] += a * wv.w;
            }
        }
    }
    float dv = pairs[v].y;
#pragma unroll
    for (int f8 = 0; f8 < 8; f8++) {
        half8 h;
#pragma unroll
        for (int i = 0; i < 8; i++) {
            int f = f8 * 8 + i;
            float val = fmaxf(dv * o[f] * sM[f] + sC[f], 0.f);
            if (prescale) val *= dv;
            h[i] = (f16)val;
        }
        *(half8*)(xout + (size_t)v * HDIM + f8 * 8) = h;
    }
}

// ======== Layer-3 aggregate, column-sliced: 16 features/pass (3.2MB L2-resident) ====
// Quad q=lane>>2 = edge slot (16/iter-j), s4=lane&3 -> 4 features (8B fp16).

__global__ __launch_bounds__(256) void agg_slice_k(
    const f16* __restrict__ x2, const int* __restrict__ ptr,
    const int* __restrict__ csr, float* __restrict__ agg3, int slice) {
    int tid = threadIdx.x;
    int lane = tid & 63;
    int v = (blockIdx.x << 2) + (tid >> 6);
    if (v >= N_NODES) return;
    int q = lane >> 2, s4 = lane & 3;
    const int coff = slice * 16 + s4 * 4;      // feature offset of this lane's 4

    int e0 = ptr[v], e1 = ptr[v + 1];
    float a0 = 0.f, a1 = 0.f, a2 = 0.f, a3 = 0.f;
    if (q == 0) {                               // self-loop (row is pre-scaled)
        half4 r = *(const half4*)(x2 + (size_t)v * HDIM + coff);
        a0 = (float)r[0]; a1 = (float)r[1]; a2 = (float)r[2]; a3 = (float)r[3];
    }
    for (int e = e0; e < e1; e += 32) {
#pragma unroll
        for (int j = 0; j < 2; j++) {
            int ee = e + j * 16 + q;
            int eidx = (ee < e1) ? ee : (e1 - 1);     // clamp: same line
            int u = __builtin_nontemporal_load(csr + eidx);
            half4 r = *(const half4*)(x2 + (size_t)u * HDIM + coff); // 8B L2-hit gather
            float cf = (ee < e1) ? 1.f : 0.f;
            a0 += cf * (float)r[0]; a1 += cf * (float)r[1];
            a2 += cf * (float)r[2]; a3 += cf * (float)r[3];
        }
    }
#pragma unroll
    for (int m = 4; m <= 32; m <<= 1) {
        a0 += __shfl_xor(a0, m); a1 += __shfl_xor(a1, m);
        a2 += __shfl_xor(a2, m); a3 += __shfl_xor(a3, m);
    }
    if (q == 0) {
        float4 r = {a0, a1, a2, a3};
        *(float4*)(agg3 + (size_t)v * HDIM + coff) = r;
    }
}

// ======== Pool (mean/max per graph) + MLP head ========

__device__ inline int lower_bound_i(const int* __restrict__ a, int n, int val) {
    int lo = 0, hi = n;
    while (lo < hi) {
        int mid = (lo + hi) >> 1;
        if (a[mid] < val) lo = mid + 1; else hi = mid;
    }
    return lo;
}

__global__ void pool_mlp_k(const f16* __restrict__ x, const int* __restrict__ batch,
                           const float* __restrict__ wl1, const float* __restrict__ bl1,
                           const float* __restrict__ wl2, const float* __restrict__ bl2,
                           const float* __restrict__ bg, const float* __restrict__ bb,
                           const float* __restrict__ brm, const float* __restrict__ brv,
                           float* __restrict__ out) {
    int g = blockIdx.x;
    int tid = threadIdx.x;
    int w = tid >> 6;
    int f = tid & 63;
    int start = lower_bound_i(batch, N_NODES, g);
    int end = lower_bound_i(batch, N_NODES, g + 1);
    float sum = 0.f;
    float mx = -3.402823466e38f;
#pragma unroll 2
    for (int v = start + w; v < end; v += 4) {
        float val = (float)x[(size_t)v * HDIM + f];
        sum += val;
        mx = fmaxf(mx, val);
    }
    __shared__ float ssum[4][HDIM], smax[4][HDIM];
    __shared__ float zs[2 * HDIM];
    ssum[w][f] = sum;
    smax[w][f] = mx;
    __syncthreads();
    if (tid < 64) {
        float sm = ssum[0][f] + ssum[1][f] + ssum[2][f] + ssum[3][f];
        float m = fmaxf(fmaxf(smax[0][f], smax[1][f]), fmaxf(smax[2][f], smax[3][f]));
        float cnt = (float)(end - start);
        zs[f] = sm / fmaxf(cnt, 1.f);
        zs[HDIM + f] = m;
    }
    __syncthreads();
    if (tid >= 64) return;

    float o = bl1[f];
#pragma unroll 8
    for (int k = 0; k < 2 * HDIM; k++) {
        o += zs[k] * wl1[k * HDIM + f];
    }
    float sc = bg[f] * rsqrtf(brv[f] + BN_EPS);
    o = fmaxf((o - brm[f]) * sc + bb[f], 0.f);

    float p0 = o * wl2[f * 2 + 0];
    float p1 = o * wl2[f * 2 + 1];
    for (int off = 32; off > 0; off >>= 1) {
        p0 += __shfl_down(p0, off);
        p1 += __shfl_down(p1, off);
    }
    if (f == 0) {
        out[g * 2 + 0] = p0 + bl2[0];
        out[g * 2 + 1] = p1 + bl2[1];
    }
}

// ======== launch ========

extern "C" void kernel_launch(void* const* d_in, const int* in_sizes, int n_in,
                              void* d_out, int out_size, void* d_ws, size_t ws_size,
                              hipStream_t stream) {
    const float* x    = (const float*)d_in[0];
    const int* src    = (const int*)d_in[1];
    const int* dst    = (const int*)d_in[2];
    const int* batch  = (const int*)d_in[3];
    const float* w1   = (const float*)d_in[4];
    const float* b1   = (const float*)d_in[5];
    const float* w2   = (const float*)d_in[6];
    const float* b2   = (const float*)d_in[7];
    const float* w3   = (const float*)d_in[8];
    const float* b3   = (const float*)d_in[9];
    const float* wl1  = (const float*)d_in[10];
    const float* bl1  = (const float*)d_in[11];
    const float* wl2  = (const float*)d_in[12];
    const float* bl2  = (const float*)d_in[13];
    const float* bn1g = (const float*)d_in[14];
    const float* bn1b = (const float*)d_in[15];
    const float* bn1rm = (const float*)d_in[16];
    const float* bn1rv = (const float*)d_in[17];
    const float* bn2g = (const float*)d_in[18];
    const float* bn2b = (const float*)d_in[19];
    const float* bn2rm = (const float*)d_in[20];
    const float* bn2rv = (const float*)d_in[21];
    const float* bn3g = (const float*)d_in[22];
    const float* bn3b = (const float*)d_in[23];
    const float* bn3rm = (const float*)d_in[24];
    const float* bn3rv = (const float*)d_in[25];
    const float* bnlg = (const float*)d_in[26];
    const float* bnlb = (const float*)d_in[27];
    const float* bnlrm = (const float*)d_in[28];
    const float* bnlrv = (const float*)d_in[29];
    float* out = (float*)d_out;

    char* ws = (char*)d_ws;
    size_t off = 0;
    auto alloc = [&](size_t bytes) -> char* {
        off = (off + 255) & ~(size_t)255;
        char* p = ws + off;
        off += bytes;
        return p;
    };
    int*    histT    = (int*)alloc((size_t)NBUCKET * NCHUNK * 4);
    int*    scannedT = (int*)alloc((size_t)NBUCKET * NCHUNK * 4);
    int*    bbase    = (int*)alloc((NBUCKET + 1) * 4);
    int*    staging  = (int*)alloc((size_t)E_EDGES * 4);
    int*    csr      = (int*)alloc((size_t)E_EDGES * 4);
    int*    ptr      = (int*)alloc(((size_t)N_NODES + 1) * 4);
    float*  dinv     = (float*)alloc((size_t)N_NODES * 4);
    float*  xtil     = (float*)alloc((size_t)N_NODES * 4);
    float2* pairs    = (float2*)alloc((size_t)N_NODES * 8);
    float2* m1c1     = (float2*)alloc((size_t)HDIM * 8);
    float*  aggbuf   = (float*)alloc((size_t)N_NODES * HDIM * 4);  // agg2 then agg3
    f16*    x2       = (f16*)alloc((size_t)N_NODES * HDIM * 2);
    f16*    x3       = (f16*)alloc((size_t)N_NODES * HDIM * 2);
    if (off > ws_size) {
        fprintf(stderr, "kernel_launch: ws too small (%zu > %zu)\n", off, ws_size);
    }

    const int NB_WV = (N_NODES + 3) / 4;      // 25000 (wave per node)
    const int NB_T  = (N_NODES + 255) / 256;  // 391 (thread per node)

    hist_k<<<NCHUNK, 256, 0, stream>>>(dst, histT);
    scanA_k<<<1, 512, 0, stream>>>(histT, bbase, w1, b1, bn1g, bn1b, bn1rm, bn1rv, m1c1);
    scanB_k<<<NBUCKET, NCHUNK, 0, stream>>>(histT, bbase, scannedT);
    scatter_k<<<NCHUNK, 256, 0, stream>>>(src, dst, scannedT, staging);
    build_k<<<NBUCKET, 256, 0, stream>>>(staging, bbase, x, ptr, dinv, xtil, csr);
    l1sum_k<<<NB_WV, 256, 0, stream>>>(ptr, csr, dinv, xtil, x, pairs);

    agg2_k<<<NB_WV, 256, 0, stream>>>(pairs, m1c1, ptr, csr, aggbuf);
    gemv_k<<<NB_T, 256, 0, stream>>>(aggbuf, pairs, x2,
                                     w2, b2, bn2g, bn2b, bn2rm, bn2rv, 1);

    for (int s = 0; s < 4; s++)
        agg_slice_k<<<NB_WV, 256, 0, stream>>>(x2, ptr, csr, aggbuf, s);
    gemv_k<<<NB_T, 256, 0, stream>>>(aggbuf, pairs, x3,
                                     w3, b3, bn3g, bn3b, bn3rm, bn3rv, 0);

    pool_mlp_k<<<N_GRAPH, 256, 0, stream>>>(x3, batch, wl1, bl1, wl2, bl2,
                                            bnlg, bnlb, bnlrm, bnlrv, out);
}

// Round 7
// 543.040 us; speedup vs baseline: 1.0534x; 1.0534x over previous
//
#include <hip/hip_runtime.h>
#include <hip/hip_bf16.h>
#include <cstdio>

#define N_NODES 100000
#define E_EDGES 3200000
#define N_GRAPH 512
#define HDIM 64
#define BN_EPS 1e-5f
#define NBUCKET ((N_NODES + 255) / 256)   // 391 buckets of 256 nodes
#define NCHUNK 256                        // edge chunks (radix partition)
#define CHUNK ((E_EDGES + NCHUNK - 1) / NCHUNK) // 12500 edges/chunk
#define SORT_CAP 12288                    // per-bucket LDS entries (mean 8192, max ~8600)

typedef _Float16 f16;
typedef _Float16 half8 __attribute__((ext_vector_type(8)));

// ======== counter-free radix partition of edges by dst>>8 ========

__global__ __launch_bounds__(256) void hist_k(const int* __restrict__ dst,
                                              int* __restrict__ histT) {
    __shared__ int h[NBUCKET];
    int c = blockIdx.x, t = threadIdx.x;
    for (int i = t; i < NBUCKET; i += 256) h[i] = 0;
    __syncthreads();
    int e0 = c * CHUNK;
    int e1 = min(e0 + CHUNK, E_EDGES);
    for (int e = e0 + t; e < e1; e += 256)
        atomicAdd(&h[__builtin_nontemporal_load(dst + e) >> 8], 1);
    __syncthreads();
    for (int i = t; i < NBUCKET; i += 256) histT[i * NCHUNK + c] = h[i];
}

// bucket totals + exclusive scan; ALSO precomputes layer-1 affine m1c1[f]
__global__ void scanA_k(const int* __restrict__ histT, int* __restrict__ bucket_base,
                        const float* __restrict__ w1, const float* __restrict__ b1,
                        const float* __restrict__ bg1, const float* __restrict__ bb1,
                        const float* __restrict__ brm1, const float* __restrict__ brv1,
                        float2* __restrict__ m1c1) {
    __shared__ int sh[512];
    int t = threadIdx.x;
    if (t < HDIM) {  // relu(m*sfull + c) = post-BN layer-1 feature
        float sc1 = bg1[t] * rsqrtf(brv1[t] + BN_EPS);
        m1c1[t] = make_float2(sc1 * w1[t], (b1[t] - brm1[t]) * sc1 + bb1[t]);
    }
    int sum = 0;
    if (t < NBUCKET) {
        const int* row = histT + t * NCHUNK;
        for (int c = 0; c < NCHUNK; c++) sum += row[c];
    }
    sh[t] = sum;
    __syncthreads();
    for (int off = 1; off < 512; off <<= 1) {
        int add = (t >= off) ? sh[t - off] : 0;
        __syncthreads();
        sh[t] += add;
        __syncthreads();
    }
    if (t < NBUCKET) bucket_base[t] = sh[t] - sum;
    if (t == 0) bucket_base[NBUCKET] = E_EDGES;
}

__global__ __launch_bounds__(NCHUNK) void scanB_k(const int* __restrict__ histT,
                                                  const int* __restrict__ bucket_base,
                                                  int* __restrict__ scannedT) {
    __shared__ int sh[NCHUNK];
    int b = blockIdx.x, t = threadIdx.x;
    int v = histT[b * NCHUNK + t];
    sh[t] = v;
    __syncthreads();
    for (int off = 1; off < NCHUNK; off <<= 1) {
        int add = (t >= off) ? sh[t - off] : 0;
        __syncthreads();
        sh[t] += add;
        __syncthreads();
    }
    scannedT[b * NCHUNK + t] = bucket_base[b] + sh[t] - v;
}

__global__ __launch_bounds__(256) void scatter_k(const int* __restrict__ src,
                                                 const int* __restrict__ dst,
                                                 const int* __restrict__ scannedT,
                                                 int* __restrict__ staging) {
    __shared__ int lcnt[NBUCKET];
    int c = blockIdx.x, t = threadIdx.x;
    for (int i = t; i < NBUCKET; i += 256) lcnt[i] = scannedT[i * NCHUNK + c];
    __syncthreads();
    int e0 = c * CHUNK;
    int e1 = min(e0 + CHUNK, E_EDGES);
    for (int e = e0 + t; e < e1; e += 256) {
        int v = __builtin_nontemporal_load(dst + e);
        int u = __builtin_nontemporal_load(src + e);
        int pos = atomicAdd(&lcnt[v >> 8], 1);       // LDS atomic
        staging[pos] = u | ((v & 255) << 17);        // 4B, ~128B runs per bucket
    }
}

// ======== per-bucket: degrees->ptr/dinv/xtil + grouped CSR sort (merged) ========

__global__ __launch_bounds__(256) void build_k(const int* __restrict__ staging,
                                               const int* __restrict__ bucket_base,
                                               const float* __restrict__ x,
                                               int* __restrict__ ptr,
                                               float* __restrict__ dinv,
                                               float* __restrict__ xtil,
                                               int* __restrict__ csr) {
    __shared__ int hn[256];
    __shared__ int sc[256];
    __shared__ int lcnt[256];
    __shared__ int lds_u[SORT_CAP];
    int t = threadIdx.x, b = blockIdx.x;
    int v0 = b << 8;
    int p0 = bucket_base[b], p1 = bucket_base[b + 1];
    int cnt = p1 - p0;
    hn[t] = 0;
    __syncthreads();
    for (int i = t; i < cnt; i += 256)
        atomicAdd(&hn[staging[p0 + i] >> 17], 1);
    __syncthreads();
    int my = hn[t];
    sc[t] = my;
    __syncthreads();
    for (int off = 1; off < 256; off <<= 1) {
        int add = (t >= off) ? sc[t - off] : 0;
        __syncthreads();
        sc[t] += add;
        __syncthreads();
    }
    int base = sc[t] - my;       // exclusive prefix within bucket
    hn[t] = base;                // hn now holds per-node bases
    lcnt[t] = 0;
    int v = v0 + t;
    if (v < N_NODES) {
        ptr[v] = p0 + base;
        float dv = rsqrtf((float)(my + 1));
        dinv[v] = dv;
        xtil[v] = dv * x[v];
    }
    if (b == NBUCKET - 1 && t == 0) ptr[N_NODES] = E_EDGES;
    __syncthreads();
    for (int i = t; i < cnt; i += 256) {
        int packed = staging[p0 + i];          // L2-hot second pass
        int u = packed & 0x1FFFF;
        int vl = packed >> 17;
        int r = atomicAdd(&lcnt[vl], 1);
        int pos = hn[vl] + r;
        if (pos < SORT_CAP) lds_u[pos] = u;
        else csr[p0 + pos] = u;                // overflow fallback (never at this scale)
    }
    __syncthreads();
    int lim = (cnt < SORT_CAP) ? cnt : SORT_CAP;
    for (int i = t; i < lim; i += 256) csr[p0 + i] = lds_u[i]; // coalesced
}

// ======== layer-1 scalar sum: pairs[v] = {sfull, dinv} (lane-parallel gather) ========

__global__ __launch_bounds__(256) void l1sum_k(const int* __restrict__ ptr,
                                               const int* __restrict__ csr,
                                               const float* __restrict__ dinv,
                                               const float* __restrict__ xtil,
                                               const float* __restrict__ x,
                                               float2* __restrict__ pairs) {
    int tid = threadIdx.x;
    int lane = tid & 63;
    int v = (blockIdx.x << 2) + (tid >> 6);
    if (v >= N_NODES) return;
    int e0 = ptr[v], e1 = ptr[v + 1];
    float a = 0.f;
    for (int e = e0 + lane; e < e1; e += 64)
        a += xtil[__builtin_nontemporal_load(csr + e)]; // 400KB L2-resident table
#pragma unroll
    for (int m = 1; m <= 32; m <<= 1) a += __shfl_xor(a, m);
    if (lane == 0) {
        float dv = dinv[v];
        pairs[v] = make_float2(dv * a + dv * dv * x[v], dv);
    }
}

// ======== Layer 2: pairs gather (800KB L2-resident) + fused @W2 + BN + ReLU ========
// x1til[u,f] = dinv_u * relu(m1[f]*sfull_u + c1[f]) reconstructed in-register.
// Octet o=lane>>3 = edge slot, s=lane&7 -> features s*8..s*8+7. Unroll 4 = 32 edges.

__global__ __launch_bounds__(256) void agg_l2_k(
    const float2* __restrict__ pairs, const float2* __restrict__ m1c1,
    f16* __restrict__ xout,
    const int* __restrict__ ptr, const int* __restrict__ csr,
    const float* __restrict__ W2, const float* __restrict__ bias2,
    const float* __restrict__ bg2, const float* __restrict__ bb2,
    const float* __restrict__ brm2, const float* __restrict__ brv2) {
    __shared__ float wsh[HDIM * HDIM];
    __shared__ float sM[HDIM], sC[HDIM];
    int tid = threadIdx.x;
    for (int i = tid; i < HDIM * HDIM; i += 256) wsh[i] = W2[i];
    if (tid < HDIM) {
        float sc = bg2[tid] * rsqrtf(brv2[tid] + BN_EPS);
        sM[tid] = sc;
        sC[tid] = (bias2[tid] - brm2[tid]) * sc + bb2[tid];
    }
    __syncthreads();

    int lane = tid & 63;
    int v = (blockIdx.x << 2) + (tid >> 6);
    if (v >= N_NODES) return;
    int o = lane >> 3, s = lane & 7;

    float m1[8], c1[8];
#pragma unroll
    for (int i = 0; i < 8; i++) {
        float2 mc = m1c1[s * 8 + i];          // contiguous 64B per octet
        m1[i] = mc.x; c1[i] = mc.y;
    }

    int e0 = ptr[v], e1 = ptr[v + 1];
    float2 pv = pairs[v];
    float acc[8];
    {
        float cf = (o == 0) ? pv.y : 0.f;     // self-loop, once
#pragma unroll
        for (int i = 0; i < 8; i++)
            acc[i] = cf * fmaxf(m1[i] * pv.x + c1[i], 0.f);
    }
    for (int e = e0; e < e1; e += 32) {
#pragma unroll
        for (int j = 0; j < 4; j++) {
            int ee = e + j * 8 + o;
            int eidx = (ee < e1) ? ee : (e1 - 1);  // clamp: same line
            int u = __builtin_nontemporal_load(csr + eidx);
            float2 p = pairs[u];                   // 8B gather, L2-resident
            float cf = (ee < e1) ? p.y : 0.f;
#pragma unroll
            for (int i = 0; i < 8; i++)
                acc[i] += cf * fmaxf(m1[i] * p.x + c1[i], 0.f);
        }
    }
#pragma unroll
    for (int i = 0; i < 8; i++) {
        acc[i] += __shfl_xor(acc[i], 8);
        acc[i] += __shfl_xor(acc[i], 16);
        acc[i] += __shfl_xor(acc[i], 32);
    }
    int f = lane;
    float ov = 0.f;
#pragma unroll
    for (int k = 0; k < HDIM; k++) {
        float a = __shfl(acc[k & 7], k >> 3);  // const lane -> v_readlane
        ov += a * wsh[(k << 6) + f];
    }
    float val = fmaxf(pv.y * ov * sM[f] + sC[f], 0.f);
    xout[(size_t)v * HDIM + f] = (f16)(pv.y * val);  // pre-scaled for layer 3
}

// ======== Layer 3: fp16 row gather (8 rows per wave-load) + fused @W3 + BN + ReLU ====

__global__ __launch_bounds__(256, 8) void agg_gemm_k(
    const f16* __restrict__ xin, f16* __restrict__ xout,
    const int* __restrict__ ptr, const int* __restrict__ csr,
    const float2* __restrict__ pairs,
    const float* __restrict__ W, const float* __restrict__ bias,
    const float* __restrict__ bg, const float* __restrict__ bb,
    const float* __restrict__ brm, const float* __restrict__ brv) {
    __shared__ float wsh[HDIM * HDIM];
    __shared__ float sM[HDIM], sC[HDIM];
    int tid = threadIdx.x;
    for (int i = tid; i < HDIM * HDIM; i += 256) wsh[i] = W[i];
    if (tid < HDIM) {
        float sc = bg[tid] * rsqrtf(brv[tid] + BN_EPS);
        sM[tid] = sc;
        sC[tid] = (bias[tid] - brm[tid]) * sc + bb[tid];
    }
    __syncthreads();

    int lane = tid & 63;
    int v = (blockIdx.x << 2) + (tid >> 6);
    if (v >= N_NODES) return;
    int o = lane >> 3, s = lane & 7;

    const half8* __restrict__ xin8 = (const half8*)xin;
    int e0 = ptr[v], e1 = ptr[v + 1];
    float acc[8];
    {
        half8 r = xin8[(size_t)v * 8 + s];     // self-loop row (broadcast load)
        float cf = (o == 0) ? 1.f : 0.f;
#pragma unroll
        for (int i = 0; i < 8; i++) acc[i] = cf * (float)r[i];
    }
    for (int e = e0; e < e1; e += 32) {
#pragma unroll
        for (int j = 0; j < 4; j++) {
            int ee = e + j * 8 + o;
            int eidx = (ee < e1) ? ee : (e1 - 1);  // clamp: same line
            int u = __builtin_nontemporal_load(csr + eidx);
            half8 r = xin8[(size_t)u * 8 + s];     // 16B/lane, 8 rows per wave-load
            float cf = (ee < e1) ? 1.f : 0.f;
#pragma unroll
            for (int i = 0; i < 8; i++) acc[i] += cf * (float)r[i];
        }
    }
#pragma unroll
    for (int i = 0; i < 8; i++) {
        acc[i] += __shfl_xor(acc[i], 8);
        acc[i] += __shfl_xor(acc[i], 16);
        acc[i] += __shfl_xor(acc[i], 32);
    }
    int f = lane;
    float ov = 0.f;
#pragma unroll
    for (int k = 0; k < HDIM; k++) {
        float a = __shfl(acc[k & 7], k >> 3);
        ov += a * wsh[(k << 6) + f];
    }
    float dv = pairs[v].y;
    float val = fmaxf(dv * ov * sM[f] + sC[f], 0.f);
    xout[(size_t)v * HDIM + f] = (f16)val;
}

// ======== Pool (mean/max per graph) + MLP head ========

__device__ inline int lower_bound_i(const int* __restrict__ a, int n, int val) {
    int lo = 0, hi = n;
    while (lo < hi) {
        int mid = (lo + hi) >> 1;
        if (a[mid] < val) lo = mid + 1; else hi = mid;
    }
    return lo;
}

__global__ void pool_mlp_k(const f16* __restrict__ x, const int* __restrict__ batch,
                           const float* __restrict__ wl1, const float* __restrict__ bl1,
                           const float* __restrict__ wl2, const float* __restrict__ bl2,
                           const float* __restrict__ bg, const float* __restrict__ bb,
                           const float* __restrict__ brm, const float* __restrict__ brv,
                           float* __restrict__ out) {
    int g = blockIdx.x;
    int tid = threadIdx.x;
    int w = tid >> 6;
    int f = tid & 63;
    int start = lower_bound_i(batch, N_NODES, g);
    int end = lower_bound_i(batch, N_NODES, g + 1);
    float sum = 0.f;
    float mx = -3.402823466e38f;
#pragma unroll 2
    for (int v = start + w; v < end; v += 4) {
        float val = (float)x[(size_t)v * HDIM + f];
        sum += val;
        mx = fmaxf(mx, val);
    }
    __shared__ float ssum[4][HDIM], smax[4][HDIM];
    __shared__ float zs[2 * HDIM];
    ssum[w][f] = sum;
    smax[w][f] = mx;
    __syncthreads();
    if (tid < 64) {
        float sm = ssum[0][f] + ssum[1][f] + ssum[2][f] + ssum[3][f];
        float m = fmaxf(fmaxf(smax[0][f], smax[1][f]), fmaxf(smax[2][f], smax[3][f]));
        float cnt = (float)(end - start);
        zs[f] = sm / fmaxf(cnt, 1.f);
        zs[HDIM + f] = m;
    }
    __syncthreads();
    if (tid >= 64) return;

    float o = bl1[f];
#pragma unroll 8
    for (int k = 0; k < 2 * HDIM; k++) {
        o += zs[k] * wl1[k * HDIM + f];
    }
    float sc = bg[f] * rsqrtf(brv[f] + BN_EPS);
    o = fmaxf((o - brm[f]) * sc + bb[f], 0.f);

    float p0 = o * wl2[f * 2 + 0];
    float p1 = o * wl2[f * 2 + 1];
    for (int off = 32; off > 0; off >>= 1) {
        p0 += __shfl_down(p0, off);
        p1 += __shfl_down(p1, off);
    }
    if (f == 0) {
        out[g * 2 + 0] = p0 + bl2[0];
        out[g * 2 + 1] = p1 + bl2[1];
    }
}

// ======== launch ========

extern "C" void kernel_launch(void* const* d_in, const int* in_sizes, int n_in,
                              void* d_out, int out_size, void* d_ws, size_t ws_size,
                              hipStream_t stream) {
    const float* x    = (const float*)d_in[0];
    const int* src    = (const int*)d_in[1];
    const int* dst    = (const int*)d_in[2];
    const int* batch  = (const int*)d_in[3];
    const float* w1   = (const float*)d_in[4];
    const float* b1   = (const float*)d_in[5];
    const float* w2   = (const float*)d_in[6];
    const float* b2   = (const float*)d_in[7];
    const float* w3   = (const float*)d_in[8];
    const float* b3   = (const float*)d_in[9];
    const float* wl1  = (const float*)d_in[10];
    const float* bl1  = (const float*)d_in[11];
    const float* wl2  = (const float*)d_in[12];
    const float* bl2  = (const float*)d_in[13];
    const float* bn1g = (const float*)d_in[14];
    const float* bn1b = (const float*)d_in[15];
    const float* bn1rm = (const float*)d_in[16];
    const float* bn1rv = (const float*)d_in[17];
    const float* bn2g = (const float*)d_in[18];
    const float* bn2b = (const float*)d_in[19];
    const float* bn2rm = (const float*)d_in[20];
    const float* bn2rv = (const float*)d_in[21];
    const float* bn3g = (const float*)d_in[22];
    const float* bn3b = (const float*)d_in[23];
    const float* bn3rm = (const float*)d_in[24];
    const float* bn3rv = (const float*)d_in[25];
    const float* bnlg = (const float*)d_in[26];
    const float* bnlb = (const float*)d_in[27];
    const float* bnlrm = (const float*)d_in[28];
    const float* bnlrv = (const float*)d_in[29];
    float* out = (float*)d_out;

    char* ws = (char*)d_ws;
    size_t off = 0;
    auto alloc = [&](size_t bytes) -> char* {
        off = (off + 255) & ~(size_t)255;
        char* p = ws + off;
        off += bytes;
        return p;
    };
    int*    histT    = (int*)alloc((size_t)NBUCKET * NCHUNK * 4);
    int*    scannedT = (int*)alloc((size_t)NBUCKET * NCHUNK * 4);
    int*    bbase    = (int*)alloc((NBUCKET + 1) * 4);
    int*    staging  = (int*)alloc((size_t)E_EDGES * 4);
    int*    csr      = (int*)alloc((size_t)E_EDGES * 4);
    int*    ptr      = (int*)alloc(((size_t)N_NODES + 1) * 4);
    float*  dinv     = (float*)alloc((size_t)N_NODES * 4);
    float*  xtil     = (float*)alloc((size_t)N_NODES * 4);
    float2* pairs    = (float2*)alloc((size_t)N_NODES * 8);
    float2* m1c1     = (float2*)alloc((size_t)HDIM * 8);
    f16*    x2       = (f16*)alloc((size_t)N_NODES * HDIM * 2);
    f16*    x3       = (f16*)alloc((size_t)N_NODES * HDIM * 2);
    if (off > ws_size) {
        fprintf(stderr, "kernel_launch: ws too small (%zu > %zu)\n", off, ws_size);
    }

    const int NB_WV = (N_NODES + 3) / 4;      // 25000 (wave per node)

    hist_k<<<NCHUNK, 256, 0, stream>>>(dst, histT);
    scanA_k<<<1, 512, 0, stream>>>(histT, bbase, w1, b1, bn1g, bn1b, bn1rm, bn1rv, m1c1);
    scanB_k<<<NBUCKET, NCHUNK, 0, stream>>>(histT, bbase, scannedT);
    scatter_k<<<NCHUNK, 256, 0, stream>>>(src, dst, scannedT, staging);
    build_k<<<NBUCKET, 256, 0, stream>>>(staging, bbase, x, ptr, dinv, xtil, csr);
    l1sum_k<<<NB_WV, 256, 0, stream>>>(ptr, csr, dinv, xtil, x, pairs);

    agg_l2_k<<<NB_WV, 256, 0, stream>>>(pairs, m1c1, x2, ptr, csr,
                                        w2, b2, bn2g, bn2b, bn2rm, bn2rv);
    agg_gemm_k<<<NB_WV, 256, 0, stream>>>(x2, x3, ptr, csr, pairs,
                                          w3, b3, bn3g, bn3b, bn3rm, bn3rv);

    pool_mlp_k<<<N_GRAPH, 256, 0, stream>>>(x3, batch, wl1, bl1, wl2, bl2,
                                            bnlg, bnlb, bnlrm, bnlrv, out);
}

// Round 8
// 522.597 us; speedup vs baseline: 1.0947x; 1.0391x over previous
//
#include <hip/hip_runtime.h>
#include <hip/hip_bf16.h>
#include <cstdio>

#define N_NODES 100000
#define E_EDGES 3200000
#define N_GRAPH 512
#define HDIM 64
#define BN_EPS 1e-5f
#define NBUCKET ((N_NODES + 255) / 256)   // 391 buckets of 256 nodes
#define NCHUNK 256                        // edge chunks (radix partition)
#define CHUNK ((E_EDGES + NCHUNK - 1) / NCHUNK) // 12500 edges/chunk
#define SORT_CAP 12288                    // per-bucket LDS entries (mean 8192, max ~8600)
#define NPW 8                             // nodes per wave in agg kernels

typedef _Float16 f16;
typedef _Float16 half8 __attribute__((ext_vector_type(8)));

// ======== counter-free radix partition of edges by dst>>8 ========

__global__ __launch_bounds__(256) void hist_k(const int* __restrict__ dst,
                                              int* __restrict__ histT) {
    __shared__ int h[NBUCKET];
    int c = blockIdx.x, t = threadIdx.x;
    for (int i = t; i < NBUCKET; i += 256) h[i] = 0;
    __syncthreads();
    int e0 = c * CHUNK;
    int e1 = min(e0 + CHUNK, E_EDGES);
    for (int e = e0 + t; e < e1; e += 256)
        atomicAdd(&h[__builtin_nontemporal_load(dst + e) >> 8], 1);
    __syncthreads();
    for (int i = t; i < NBUCKET; i += 256) histT[i * NCHUNK + c] = h[i];
}

// bucket totals + exclusive scan; ALSO precomputes layer-1 affine m1c1[f]
__global__ void scanA_k(const int* __restrict__ histT, int* __restrict__ bucket_base,
                        const float* __restrict__ w1, const float* __restrict__ b1,
                        const float* __restrict__ bg1, const float* __restrict__ bb1,
                        const float* __restrict__ brm1, const float* __restrict__ brv1,
                        float2* __restrict__ m1c1) {
    __shared__ int sh[512];
    int t = threadIdx.x;
    if (t < HDIM) {  // relu(m*sfull + c) = post-BN layer-1 feature
        float sc1 = bg1[t] * rsqrtf(brv1[t] + BN_EPS);
        m1c1[t] = make_float2(sc1 * w1[t], (b1[t] - brm1[t]) * sc1 + bb1[t]);
    }
    int sum = 0;
    if (t < NBUCKET) {
        const int* row = histT + t * NCHUNK;
        for (int c = 0; c < NCHUNK; c++) sum += row[c];
    }
    sh[t] = sum;
    __syncthreads();
    for (int off = 1; off < 512; off <<= 1) {
        int add = (t >= off) ? sh[t - off] : 0;
        __syncthreads();
        sh[t] += add;
        __syncthreads();
    }
    if (t < NBUCKET) bucket_base[t] = sh[t] - sum;
    if (t == 0) bucket_base[NBUCKET] = E_EDGES;
}

__global__ __launch_bounds__(NCHUNK) void scanB_k(const int* __restrict__ histT,
                                                  const int* __restrict__ bucket_base,
                                                  int* __restrict__ scannedT) {
    __shared__ int sh[NCHUNK];
    int b = blockIdx.x, t = threadIdx.x;
    int v = histT[b * NCHUNK + t];
    sh[t] = v;
    __syncthreads();
    for (int off = 1; off < NCHUNK; off <<= 1) {
        int add = (t >= off) ? sh[t - off] : 0;
        __syncthreads();
        sh[t] += add;
        __syncthreads();
    }
    scannedT[b * NCHUNK + t] = bucket_base[b] + sh[t] - v;
}

__global__ __launch_bounds__(256) void scatter_k(const int* __restrict__ src,
                                                 const int* __restrict__ dst,
                                                 const int* __restrict__ scannedT,
                                                 int* __restrict__ staging) {
    __shared__ int lcnt[NBUCKET];
    int c = blockIdx.x, t = threadIdx.x;
    for (int i = t; i < NBUCKET; i += 256) lcnt[i] = scannedT[i * NCHUNK + c];
    __syncthreads();
    int e0 = c * CHUNK;
    int e1 = min(e0 + CHUNK, E_EDGES);
    for (int e = e0 + t; e < e1; e += 256) {
        int v = __builtin_nontemporal_load(dst + e);
        int u = __builtin_nontemporal_load(src + e);
        int pos = atomicAdd(&lcnt[v >> 8], 1);       // LDS atomic
        staging[pos] = u | ((v & 255) << 17);        // 4B, ~128B runs per bucket
    }
}

// ======== per-bucket: node degrees -> ptr/dinv/xtil ========

__global__ __launch_bounds__(256) void nodeptr_k(const int* __restrict__ staging,
                                                 const int* __restrict__ bucket_base,
                                                 const float* __restrict__ x,
                                                 int* __restrict__ ptr,
                                                 float* __restrict__ dinv,
                                                 float* __restrict__ xtil) {
    __shared__ int hn[256];
    __shared__ int sc[256];
    int t = threadIdx.x, b = blockIdx.x;
    int v0 = b << 8;
    int p0 = bucket_base[b], p1 = bucket_base[b + 1];
    hn[t] = 0;
    __syncthreads();
    int cnt = p1 - p0;
    for (int i = t; i < cnt; i += 256)
        atomicAdd(&hn[staging[p0 + i] >> 17], 1);
    __syncthreads();
    int my = hn[t];
    sc[t] = my;
    __syncthreads();
    for (int off = 1; off < 256; off <<= 1) {
        int add = (t >= off) ? sc[t - off] : 0;
        __syncthreads();
        sc[t] += add;
        __syncthreads();
    }
    int v = v0 + t;
    if (v < N_NODES) {
        ptr[v] = p0 + sc[t] - my;
        float dv = rsqrtf((float)(my + 1));
        dinv[v] = dv;
        xtil[v] = dv * x[v];
    }
    if (b == NBUCKET - 1 && t == 0) ptr[N_NODES] = E_EDGES;
}

// ======== per-bucket: grouped CSR write + fused layer-1 scalar sum -> pairs ========

__global__ __launch_bounds__(256) void csr_l1_k(const int* __restrict__ staging,
                                                const int* __restrict__ ptr,
                                                const int* __restrict__ bucket_base,
                                                const float* __restrict__ dinv,
                                                const float* __restrict__ xtil,
                                                const float* __restrict__ x,
                                                int* __restrict__ csr,
                                                float2* __restrict__ pairs) {
    __shared__ int lbase[257];
    __shared__ int lcnt[256];
    __shared__ int lds_u[SORT_CAP];
    int t = threadIdx.x, b = blockIdx.x;
    int v0 = b << 8;
    int p0 = bucket_base[b];
    for (int i = t; i < 257; i += 256) {
        int vv = v0 + i;
        lbase[i] = ((vv < N_NODES) ? ptr[vv] : E_EDGES) - p0;
    }
    lcnt[t] = 0;
    __syncthreads();
    int cnt = lbase[256];
    for (int i = t; i < cnt; i += 256) {
        int packed = staging[p0 + i];          // L2-hot re-read
        int u = packed & 0x1FFFF;
        int vl = packed >> 17;
        int r = atomicAdd(&lcnt[vl], 1);       // LDS atomic
        int pos = lbase[vl] + r;
        if (pos < SORT_CAP) lds_u[pos] = u;
        else csr[p0 + pos] = u;                // overflow fallback (never at this scale)
    }
    __syncthreads();
    int lim = (cnt < SORT_CAP) ? cnt : SORT_CAP;
    for (int i = t; i < lim; i += 256) csr[p0 + i] = lds_u[i]; // coalesced
    __syncthreads();
    // layer 1 (rank-1): sfull[v] = dv * sum(xtil[u]) + dv^2 * x[v], from LDS-resident u's
    int v = v0 + t;
    if (v < N_NODES) {
        int j0 = lbase[t], j1 = lbase[t + 1];
        float s = 0.f;
        for (int j = j0; j < j1; j++) {
            int u = (j < SORT_CAP) ? lds_u[j] : csr[p0 + j];
            s += xtil[u];                      // 400KB L2-resident table
        }
        float dv = dinv[v];
        pairs[v] = make_float2(dv * s + dv * dv * x[v], dv);
    }
}

// ======== Layer 2: pairs gather (800KB L2-resident) + fused @W2 + BN + ReLU ========
// x1til[u,f] = dinv_u * relu(m1[f]*sfull_u + c1[f]) reconstructed in-register.
// Octet o=lane>>3 = edge slot, s=lane&7 -> features s*8..s*8+7. NPW nodes per wave
// amortize the 16KB W2 staging across 8x more work per block.

__global__ __launch_bounds__(256) void agg_l2_k(
    const float2* __restrict__ pairs, const float2* __restrict__ m1c1,
    f16* __restrict__ xout,
    const int* __restrict__ ptr, const int* __restrict__ csr,
    const float* __restrict__ W2, const float* __restrict__ bias2,
    const float* __restrict__ bg2, const float* __restrict__ bb2,
    const float* __restrict__ brm2, const float* __restrict__ brv2) {
    __shared__ float wsh[HDIM * HDIM];
    __shared__ float sM[HDIM], sC[HDIM];
    int tid = threadIdx.x;
    for (int i = tid; i < HDIM * HDIM; i += 256) wsh[i] = W2[i];
    if (tid < HDIM) {
        float sc = bg2[tid] * rsqrtf(brv2[tid] + BN_EPS);
        sM[tid] = sc;
        sC[tid] = (bias2[tid] - brm2[tid]) * sc + bb2[tid];
    }
    __syncthreads();

    int lane = tid & 63;
    int o = lane >> 3, s = lane & 7;
    int f = lane;

    float m1[8], c1[8];
#pragma unroll
    for (int i = 0; i < 8; i++) {
        float2 mc = m1c1[s * 8 + i];          // contiguous 64B per octet
        m1[i] = mc.x; c1[i] = mc.y;
    }

    int v0 = (blockIdx.x * 4 + (tid >> 6)) * NPW;
    for (int n = 0; n < NPW; n++) {
        int v = v0 + n;
        if (v >= N_NODES) break;
        int e0 = ptr[v], e1 = ptr[v + 1];     // wave-uniform -> scalar loads
        float2 pv = pairs[v];
        float acc[8];
        {
            float cf = (o == 0) ? pv.y : 0.f; // self-loop, once
#pragma unroll
            for (int i = 0; i < 8; i++)
                acc[i] = cf * fmaxf(m1[i] * pv.x + c1[i], 0.f);
        }
        for (int e = e0; e < e1; e += 32) {
#pragma unroll
            for (int j = 0; j < 4; j++) {
                int ee = e + j * 8 + o;
                int eidx = (ee < e1) ? ee : (e1 - 1);  // clamp: same line
                int u = __builtin_nontemporal_load(csr + eidx);
                float2 p = pairs[u];                   // 8B gather, L2-resident
                float cf = (ee < e1) ? p.y : 0.f;
#pragma unroll
                for (int i = 0; i < 8; i++)
                    acc[i] += cf * fmaxf(m1[i] * p.x + c1[i], 0.f);
            }
        }
#pragma unroll
        for (int i = 0; i < 8; i++) {
            acc[i] += __shfl_xor(acc[i], 8);
            acc[i] += __shfl_xor(acc[i], 16);
            acc[i] += __shfl_xor(acc[i], 32);
        }
        float ov = 0.f;
#pragma unroll
        for (int k = 0; k < HDIM; k++) {
            float a = __shfl(acc[k & 7], k >> 3);  // const lane -> v_readlane
            ov += a * wsh[(k << 6) + f];
        }
        float val = fmaxf(pv.y * ov * sM[f] + sC[f], 0.f);
        xout[(size_t)v * HDIM + f] = (f16)(pv.y * val);  // pre-scaled for layer 3
    }
}

// ======== Layer 3: fp16 row gather (8 rows per wave-load) + fused @W3 + BN + ReLU ====

__global__ __launch_bounds__(256, 8) void agg_gemm_k(
    const f16* __restrict__ xin, f16* __restrict__ xout,
    const int* __restrict__ ptr, const int* __restrict__ csr,
    const float2* __restrict__ pairs,
    const float* __restrict__ W, const float* __restrict__ bias,
    const float* __restrict__ bg, const float* __restrict__ bb,
    const float* __restrict__ brm, const float* __restrict__ brv) {
    __shared__ float wsh[HDIM * HDIM];
    __shared__ float sM[HDIM], sC[HDIM];
    int tid = threadIdx.x;
    for (int i = tid; i < HDIM * HDIM; i += 256) wsh[i] = W[i];
    if (tid < HDIM) {
        float sc = bg[tid] * rsqrtf(brv[tid] + BN_EPS);
        sM[tid] = sc;
        sC[tid] = (bias[tid] - brm[tid]) * sc + bb[tid];
    }
    __syncthreads();

    int lane = tid & 63;
    int o = lane >> 3, s = lane & 7;
    int f = lane;
    const half8* __restrict__ xin8 = (const half8*)xin;

    int v0 = (blockIdx.x * 4 + (tid >> 6)) * NPW;
    for (int n = 0; n < NPW; n++) {
        int v = v0 + n;
        if (v >= N_NODES) break;
        int e0 = ptr[v], e1 = ptr[v + 1];
        float acc[8];
        {
            half8 r = xin8[(size_t)v * 8 + s];     // self-loop row (broadcast load)
            float cf = (o == 0) ? 1.f : 0.f;
#pragma unroll
            for (int i = 0; i < 8; i++) acc[i] = cf * (float)r[i];
        }
        for (int e = e0; e < e1; e += 32) {
#pragma unroll
            for (int j = 0; j < 4; j++) {
                int ee = e + j * 8 + o;
                int eidx = (ee < e1) ? ee : (e1 - 1);  // clamp: same line
                int u = __builtin_nontemporal_load(csr + eidx);
                half8 r = xin8[(size_t)u * 8 + s];     // 16B/lane, 8 rows per wave-load
                float cf = (ee < e1) ? 1.f : 0.f;
#pragma unroll
                for (int i = 0; i < 8; i++) acc[i] += cf * (float)r[i];
            }
        }
#pragma unroll
        for (int i = 0; i < 8; i++) {
            acc[i] += __shfl_xor(acc[i], 8);
            acc[i] += __shfl_xor(acc[i], 16);
            acc[i] += __shfl_xor(acc[i], 32);
        }
        float ov = 0.f;
#pragma unroll
        for (int k = 0; k < HDIM; k++) {
            float a = __shfl(acc[k & 7], k >> 3);
            ov += a * wsh[(k << 6) + f];
        }
        float dv = pairs[v].y;
        float val = fmaxf(dv * ov * sM[f] + sC[f], 0.f);
        xout[(size_t)v * HDIM + f] = (f16)val;
    }
}

// ======== Pool (mean/max per graph) + MLP head ========

__device__ inline int lower_bound_i(const int* __restrict__ a, int n, int val) {
    int lo = 0, hi = n;
    while (lo < hi) {
        int mid = (lo + hi) >> 1;
        if (a[mid] < val) lo = mid + 1; else hi = mid;
    }
    return lo;
}

__global__ void pool_mlp_k(const f16* __restrict__ x, const int* __restrict__ batch,
                           const float* __restrict__ wl1, const float* __restrict__ bl1,
                           const float* __restrict__ wl2, const float* __restrict__ bl2,
                           const float* __restrict__ bg, const float* __restrict__ bb,
                           const float* __restrict__ brm, const float* __restrict__ brv,
                           float* __restrict__ out) {
    int g = blockIdx.x;
    int tid = threadIdx.x;
    int w = tid >> 6;
    int f = tid & 63;
    int start = lower_bound_i(batch, N_NODES, g);
    int end = lower_bound_i(batch, N_NODES, g + 1);
    float sum = 0.f;
    float mx = -3.402823466e38f;
#pragma unroll 2
    for (int v = start + w; v < end; v += 4) {
        float val = (float)x[(size_t)v * HDIM + f];
        sum += val;
        mx = fmaxf(mx, val);
    }
    __shared__ float ssum[4][HDIM], smax[4][HDIM];
    __shared__ float zs[2 * HDIM];
    ssum[w][f] = sum;
    smax[w][f] = mx;
    __syncthreads();
    if (tid < 64) {
        float sm = ssum[0][f] + ssum[1][f] + ssum[2][f] + ssum[3][f];
        float m = fmaxf(fmaxf(smax[0][f], smax[1][f]), fmaxf(smax[2][f], smax[3][f]));
        float cnt = (float)(end - start);
        zs[f] = sm / fmaxf(cnt, 1.f);
        zs[HDIM + f] = m;
    }
    __syncthreads();
    if (tid >= 64) return;

    float o = bl1[f];
#pragma unroll 8
    for (int k = 0; k < 2 * HDIM; k++) {
        o += zs[k] * wl1[k * HDIM + f];
    }
    float sc = bg[f] * rsqrtf(brv[f] + BN_EPS);
    o = fmaxf((o - brm[f]) * sc + bb[f], 0.f);

    float p0 = o * wl2[f * 2 + 0];
    float p1 = o * wl2[f * 2 + 1];
    for (int off = 32; off > 0; off >>= 1) {
        p0 += __shfl_down(p0, off);
        p1 += __shfl_down(p1, off);
    }
    if (f == 0) {
        out[g * 2 + 0] = p0 + bl2[0];
        out[g * 2 + 1] = p1 + bl2[1];
    }
}

// ======== launch ========

extern "C" void kernel_launch(void* const* d_in, const int* in_sizes, int n_in,
                              void* d_out, int out_size, void* d_ws, size_t ws_size,
                              hipStream_t stream) {
    const float* x    = (const float*)d_in[0];
    const int* src    = (const int*)d_in[1];
    const int* dst    = (const int*)d_in[2];
    const int* batch  = (const int*)d_in[3];
    const float* w1   = (const float*)d_in[4];
    const float* b1   = (const float*)d_in[5];
    const float* w2   = (const float*)d_in[6];
    const float* b2   = (const float*)d_in[7];
    const float* w3   = (const float*)d_in[8];
    const float* b3   = (const float*)d_in[9];
    const float* wl1  = (const float*)d_in[10];
    const float* bl1  = (const float*)d_in[11];
    const float* wl2  = (const float*)d_in[12];
    const float* bl2  = (const float*)d_in[13];
    const float* bn1g = (const float*)d_in[14];
    const float* bn1b = (const float*)d_in[15];
    const float* bn1rm = (const float*)d_in[16];
    const float* bn1rv = (const float*)d_in[17];
    const float* bn2g = (const float*)d_in[18];
    const float* bn2b = (const float*)d_in[19];
    const float* bn2rm = (const float*)d_in[20];
    const float* bn2rv = (const float*)d_in[21];
    const float* bn3g = (const float*)d_in[22];
    const float* bn3b = (const float*)d_in[23];
    const float* bn3rm = (const float*)d_in[24];
    const float* bn3rv = (const float*)d_in[25];
    const float* bnlg = (const float*)d_in[26];
    const float* bnlb = (const float*)d_in[27];
    const float* bnlrm = (const float*)d_in[28];
    const float* bnlrv = (const float*)d_in[29];
    float* out = (float*)d_out;

    char* ws = (char*)d_ws;
    size_t off = 0;
    auto alloc = [&](size_t bytes) -> char* {
        off = (off + 255) & ~(size_t)255;
        char* p = ws + off;
        off += bytes;
        return p;
    };
    int*    histT    = (int*)alloc((size_t)NBUCKET * NCHUNK * 4);
    int*    scannedT = (int*)alloc((size_t)NBUCKET * NCHUNK * 4);
    int*    bbase    = (int*)alloc((NBUCKET + 1) * 4);
    int*    staging  = (int*)alloc((size_t)E_EDGES * 4);
    int*    csr      = (int*)alloc((size_t)E_EDGES * 4);
    int*    ptr      = (int*)alloc(((size_t)N_NODES + 1) * 4);
    float*  dinv     = (float*)alloc((size_t)N_NODES * 4);
    float*  xtil     = (float*)alloc((size_t)N_NODES * 4);
    float2* pairs    = (float2*)alloc((size_t)N_NODES * 8);
    float2* m1c1     = (float2*)alloc((size_t)HDIM * 8);
    f16*    x2       = (f16*)alloc((size_t)N_NODES * HDIM * 2);
    f16*    x3       = (f16*)alloc((size_t)N_NODES * HDIM * 2);
    if (off > ws_size) {
        fprintf(stderr, "kernel_launch: ws too small (%zu > %zu)\n", off, ws_size);
    }

    const int NB_AGG = (N_NODES + 4 * NPW - 1) / (4 * NPW);  // 3125

    hist_k<<<NCHUNK, 256, 0, stream>>>(dst, histT);
    scanA_k<<<1, 512, 0, stream>>>(histT, bbase, w1, b1, bn1g, bn1b, bn1rm, bn1rv, m1c1);
    scanB_k<<<NBUCKET, NCHUNK, 0, stream>>>(histT, bbase, scannedT);
    scatter_k<<<NCHUNK, 256, 0, stream>>>(src, dst, scannedT, staging);
    nodeptr_k<<<NBUCKET, 256, 0, stream>>>(staging, bbase, x, ptr, dinv, xtil);
    csr_l1_k<<<NBUCKET, 256, 0, stream>>>(staging, ptr, bbase, dinv, xtil, x, csr, pairs);

    agg_l2_k<<<NB_AGG, 256, 0, stream>>>(pairs, m1c1, x2, ptr, csr,
                                         w2, b2, bn2g, bn2b, bn2rm, bn2rv);
    agg_gemm_k<<<NB_AGG, 256, 0, stream>>>(x2, x3, ptr, csr, pairs,
                                           w3, b3, bn3g, bn3b, bn3rm, bn3rv);

    pool_mlp_k<<<N_GRAPH, 256, 0, stream>>>(x3, batch, wl1, bl1, wl2, bl2,
                                            bnlg, bnlb, bnlrm, bnlrv, out);
}

// Round 9
// 508.848 us; speedup vs baseline: 1.1242x; 1.0270x over previous
//
#include <hip/hip_runtime.h>
#include <hip/hip_bf16.h>
#include <cstdio>

#define N_NODES 100000
#define E_EDGES 3200000
#define N_GRAPH 512
#define HDIM 64
#define BN_EPS 1e-5f
#define NBUCKET ((N_NODES + 255) / 256)   // 391 buckets of 256 nodes
#define NCHUNK 256                        // edge chunks (radix partition)
#define CHUNK ((E_EDGES + NCHUNK - 1) / NCHUNK) // 12500 edges/chunk
#define SORT_CAP 12288                    // per-bucket LDS entries (padded max ~9.6k)
#define NPW 8                             // nodes per wave in agg kernels
#define WT_STRIDE 68                      // padded LDS stride for transposed W (16B-aligned, 8-touch/bank optimal)

typedef _Float16 f16;
typedef _Float16 half8 __attribute__((ext_vector_type(8)));

// ======== counter-free radix partition of edges by dst>>8 ========

__global__ __launch_bounds__(256) void hist_k(const int* __restrict__ dst,
                                              int* __restrict__ histT) {
    __shared__ int h[NBUCKET];
    int c = blockIdx.x, t = threadIdx.x;
    for (int i = t; i < NBUCKET; i += 256) h[i] = 0;
    __syncthreads();
    int e0 = c * CHUNK;
    int e1 = min(e0 + CHUNK, E_EDGES);
    for (int e = e0 + t; e < e1; e += 256)
        atomicAdd(&h[__builtin_nontemporal_load(dst + e) >> 8], 1);
    __syncthreads();
    for (int i = t; i < NBUCKET; i += 256) histT[i * NCHUNK + c] = h[i];
}

// raw bucket totals + exclusive scan; ALSO precomputes layer-1 affine m1c1[f]
__global__ void scanA_k(const int* __restrict__ histT, int* __restrict__ bucket_base,
                        const float* __restrict__ w1, const float* __restrict__ b1,
                        const float* __restrict__ bg1, const float* __restrict__ bb1,
                        const float* __restrict__ brm1, const float* __restrict__ brv1,
                        float2* __restrict__ m1c1) {
    __shared__ int sh[512];
    int t = threadIdx.x;
    if (t < HDIM) {
        float sc1 = bg1[t] * rsqrtf(brv1[t] + BN_EPS);
        m1c1[t] = make_float2(sc1 * w1[t], (b1[t] - brm1[t]) * sc1 + bb1[t]);
    }
    int sum = 0;
    if (t < NBUCKET) {
        const int* row = histT + t * NCHUNK;
        for (int c = 0; c < NCHUNK; c++) sum += row[c];
    }
    sh[t] = sum;
    __syncthreads();
    for (int off = 1; off < 512; off <<= 1) {
        int add = (t >= off) ? sh[t - off] : 0;
        __syncthreads();
        sh[t] += add;
        __syncthreads();
    }
    if (t < NBUCKET) bucket_base[t] = sh[t] - sum;
    if (t == 0) bucket_base[NBUCKET] = E_EDGES;
}

__global__ __launch_bounds__(NCHUNK) void scanB_k(const int* __restrict__ histT,
                                                  const int* __restrict__ bucket_base,
                                                  int* __restrict__ scannedT) {
    __shared__ int sh[NCHUNK];
    int b = blockIdx.x, t = threadIdx.x;
    int v = histT[b * NCHUNK + t];
    sh[t] = v;
    __syncthreads();
    for (int off = 1; off < NCHUNK; off <<= 1) {
        int add = (t >= off) ? sh[t - off] : 0;
        __syncthreads();
        sh[t] += add;
        __syncthreads();
    }
    scannedT[b * NCHUNK + t] = bucket_base[b] + sh[t] - v;
}

__global__ __launch_bounds__(256) void scatter_k(const int* __restrict__ src,
                                                 const int* __restrict__ dst,
                                                 const int* __restrict__ scannedT,
                                                 int* __restrict__ staging) {
    __shared__ int lcnt[NBUCKET];
    int c = blockIdx.x, t = threadIdx.x;
    for (int i = t; i < NBUCKET; i += 256) lcnt[i] = scannedT[i * NCHUNK + c];
    __syncthreads();
    int e0 = c * CHUNK;
    int e1 = min(e0 + CHUNK, E_EDGES);
    for (int e = e0 + t; e < e1; e += 256) {
        int v = __builtin_nontemporal_load(dst + e);
        int u = __builtin_nontemporal_load(src + e);
        int pos = atomicAdd(&lcnt[v >> 8], 1);       // LDS atomic
        staging[pos] = u | ((v & 255) << 17);        // 4B, ~128B runs per bucket
    }
}

// ======== per-bucket: node degrees -> ptr_raw/dinv/xtil + padded bucket totals ========

__global__ __launch_bounds__(256) void nodeptr_k(const int* __restrict__ staging,
                                                 const int* __restrict__ bucket_base,
                                                 const float* __restrict__ x,
                                                 int* __restrict__ ptr_raw,
                                                 float* __restrict__ dinv,
                                                 float* __restrict__ xtil,
                                                 int* __restrict__ pbt) {
    __shared__ int hn[256];
    __shared__ int sc[256];
    int t = threadIdx.x, b = blockIdx.x;
    int v0 = b << 8;
    int p0 = bucket_base[b], p1 = bucket_base[b + 1];
    hn[t] = 0;
    __syncthreads();
    int cnt = p1 - p0;
    for (int i = t; i < cnt; i += 256)
        atomicAdd(&hn[staging[p0 + i] >> 17], 1);
    __syncthreads();
    int my = hn[t];
    sc[t] = my;
    __syncthreads();
    for (int off = 1; off < 256; off <<= 1) {
        int add = (t >= off) ? sc[t - off] : 0;
        __syncthreads();
        sc[t] += add;
        __syncthreads();
    }
    int v = v0 + t;
    if (v < N_NODES) {
        ptr_raw[v] = p0 + sc[t] - my;
        float dv = rsqrtf((float)(my + 1));
        dinv[v] = dv;
        xtil[v] = dv * x[v];
    }
    if (b == NBUCKET - 1 && t == 0) ptr_raw[N_NODES] = E_EDGES;
    // padded bucket total
    int pd = (my + 3) & ~3;
    __syncthreads();
    sc[t] = pd;
    __syncthreads();
    for (int off = 1; off < 256; off <<= 1) {
        int add = (t >= off) ? sc[t - off] : 0;
        __syncthreads();
        sc[t] += add;
        __syncthreads();
    }
    if (t == 255) pbt[b] = sc[255];
}

// exclusive scan of padded bucket totals -> pbbase
__global__ void scanC_k(const int* __restrict__ pbt, int* __restrict__ pbbase,
                        int* __restrict__ ptr_pad) {
    __shared__ int sh[512];
    int t = threadIdx.x;
    int v = (t < NBUCKET) ? pbt[t] : 0;
    sh[t] = v;
    __syncthreads();
    for (int off = 1; off < 512; off <<= 1) {
        int add = (t >= off) ? sh[t - off] : 0;
        __syncthreads();
        sh[t] += add;
        __syncthreads();
    }
    if (t < NBUCKET) pbbase[t] = sh[t] - v;
    if (t == NBUCKET - 1) {
        pbbase[NBUCKET] = sh[t];
        ptr_pad[N_NODES] = sh[t];
    }
}

// ======== per-bucket: grouped PADDED CSR write (sentinel pads) + fused layer-1 sum ====

__global__ __launch_bounds__(256) void csr_l1_k(const int* __restrict__ staging,
                                                const int* __restrict__ ptr_raw,
                                                const int* __restrict__ bucket_base,
                                                const int* __restrict__ pbbase,
                                                const float* __restrict__ dinv,
                                                const float* __restrict__ xtil,
                                                const float* __restrict__ x,
                                                int* __restrict__ csr,
                                                int* __restrict__ ptr_pad,
                                                float2* __restrict__ pairs) {
    __shared__ int lbase[257];
    __shared__ int plp[257];
    __shared__ int ss[256];
    __shared__ int lcnt[256];
    __shared__ int lds_u[SORT_CAP];
    int t = threadIdx.x, b = blockIdx.x;
    int v0 = b << 8;
    int p0 = bucket_base[b];
    int pb0 = pbbase[b];
    for (int i = t; i < 257; i += 256) {
        int vv = v0 + i;
        lbase[i] = ptr_raw[(vv < N_NODES) ? vv : N_NODES] - p0;
    }
    lcnt[t] = 0;
    __syncthreads();
    int deg = lbase[t + 1] - lbase[t];
    int pd = (deg + 3) & ~3;
    ss[t] = pd;
    __syncthreads();
    for (int off = 1; off < 256; off <<= 1) {
        int add = (t >= off) ? ss[t - off] : 0;
        __syncthreads();
        ss[t] += add;
        __syncthreads();
    }
    plp[t] = ss[t] - pd;                  // exclusive padded prefix
    if (t == 255) plp[256] = ss[255];
    __syncthreads();
    int pcnt = plp[256];
    int cnt = lbase[256];
    // init LDS to sentinel (pads survive the scatter)
    int4 sent = {N_NODES, N_NODES, N_NODES, N_NODES};
    int lim4 = min(pcnt, SORT_CAP) >> 2;
    for (int i = t; i < lim4; i += 256) ((int4*)lds_u)[i] = sent;
    __syncthreads();
    for (int i = t; i < cnt; i += 256) {
        int packed = staging[p0 + i];      // L2-hot re-read
        int u = packed & 0x1FFFF;
        int vl = packed >> 17;
        int r = atomicAdd(&lcnt[vl], 1);   // LDS atomic
        int pos = plp[vl] + r;
        if (pos < SORT_CAP) lds_u[pos] = u;
        else csr[pb0 + pos] = u;           // overflow fallback (never at this scale)
    }
    __syncthreads();
    for (int i = t; i < lim4; i += 256)
        ((int4*)(csr + pb0))[i] = ((int4*)lds_u)[i];   // coalesced 16B copy
    __syncthreads();
    int v = v0 + t;
    if (v < N_NODES) {
        int j0 = plp[t];
        // overflow pad sentinels (no-op normally)
        for (int j = j0 + deg; j < j0 + pd; j++)
            if (j >= SORT_CAP) csr[pb0 + j] = N_NODES;
        ptr_pad[v] = pb0 + j0;
        float s = 0.f;
        for (int j = j0; j < j0 + deg; j++) {
            int u = (j < SORT_CAP) ? lds_u[j] : csr[pb0 + j];
            s += xtil[u];                  // 400KB L2-resident table
        }
        float dv = dinv[v];
        pairs[v] = make_float2(dv * s + dv * dv * x[v], dv);
    }
    if (b == 0 && t == 0) pairs[N_NODES] = make_float2(0.f, 0.f);  // sentinel
}

// ======== Layer 2: pairs gather + relu-reconstruct + fused @W2 + BN + ReLU ========
// int4 csr loads (4 edges/load), sentinel pads -> no masks. Octet o=lane>>3 = edge
// quad slot, s=lane&7 -> features s*8..s*8+7. Epilogue: transposed W in LDS, b128.

__global__ __launch_bounds__(256, 8) void agg_l2_k(
    const float2* __restrict__ pairs, const float2* __restrict__ m1c1,
    f16* __restrict__ xout,
    const int* __restrict__ ptr_pad, const int* __restrict__ csr,
    const float* __restrict__ W2, const float* __restrict__ bias2,
    const float* __restrict__ bg2, const float* __restrict__ bb2,
    const float* __restrict__ brm2, const float* __restrict__ brv2) {
    __shared__ float wsh_t[HDIM * WT_STRIDE];
    __shared__ float sM[HDIM], sC[HDIM];
    int tid = threadIdx.x;
    for (int i = tid; i < HDIM * HDIM; i += 256)
        wsh_t[(i & 63) * WT_STRIDE + (i >> 6)] = W2[i];    // transpose: [f][k]
    if (tid < HDIM) {
        float sc = bg2[tid] * rsqrtf(brv2[tid] + BN_EPS);
        sM[tid] = sc;
        sC[tid] = (bias2[tid] - brm2[tid]) * sc + bb2[tid];
    }
    __syncthreads();

    int lane = tid & 63;
    int o = lane >> 3, s = lane & 7;
    int f = lane;
    // sentinel row of xout (read by layer 3)
    if (blockIdx.x == 0 && tid < HDIM) xout[(size_t)N_NODES * HDIM + tid] = (f16)0.f;

    float m1[8], c1[8];
#pragma unroll
    for (int i = 0; i < 8; i++) {
        float2 mc = m1c1[s * 8 + i];
        m1[i] = mc.x; c1[i] = mc.y;
    }

    int v0 = (blockIdx.x * 4 + (tid >> 6)) * NPW;
    for (int n = 0; n < NPW; n++) {
        int v = v0 + n;
        if (v >= N_NODES) break;
        int e0 = ptr_pad[v], pe1 = ptr_pad[v + 1];  // wave-uniform
        float2 pv = pairs[v];
        float acc[8];
        {
            float cf = (o == 0) ? pv.y : 0.f;       // self-loop, once
#pragma unroll
            for (int i = 0; i < 8; i++)
                acc[i] = cf * fmaxf(m1[i] * pv.x + c1[i], 0.f);
        }
        for (int e = e0; e < pe1; e += 32) {
            int bb = e + o * 4;
            if (bb < pe1) {
                int4 u4 = *(const int4*)(csr + bb); // 16B, one load per 4 edges
                int uu[4] = {u4.x, u4.y, u4.z, u4.w};
#pragma unroll
                for (int c = 0; c < 4; c++) {
                    float2 p = pairs[uu[c]];        // 8B gather, L2-resident; sentinel->0
#pragma unroll
                    for (int i = 0; i < 8; i++)
                        acc[i] += p.y * fmaxf(m1[i] * p.x + c1[i], 0.f);
                }
            }
        }
#pragma unroll
        for (int i = 0; i < 8; i++) {
            acc[i] += __shfl_xor(acc[i], 8);
            acc[i] += __shfl_xor(acc[i], 16);
            acc[i] += __shfl_xor(acc[i], 32);
        }
        // epilogue: ov_f = sum_k a_k * Wt[f][k], Wt rows contiguous -> 16x ds_read_b128
        const float4* wt4 = (const float4*)&wsh_t[f * WT_STRIDE];
        float ov = 0.f;
#pragma unroll
        for (int k4 = 0; k4 < 16; k4++) {
            float4 w4 = wt4[k4];
            float wc[4] = {w4.x, w4.y, w4.z, w4.w};
#pragma unroll
            for (int j = 0; j < 4; j++) {
                int k = k4 * 4 + j;
                ov += __shfl(acc[k & 7], k >> 3) * wc[j];  // v_readlane + fmac
            }
        }
        float val = fmaxf(pv.y * ov * sM[f] + sC[f], 0.f);
        xout[(size_t)v * HDIM + f] = (f16)(pv.y * val);    // pre-scaled for layer 3
    }
}

// ======== Layer 3: fp16 row gather + fused @W3 + BN + ReLU ========

__global__ __launch_bounds__(256, 8) void agg_gemm_k(
    const f16* __restrict__ xin, f16* __restrict__ xout,
    const int* __restrict__ ptr_pad, const int* __restrict__ csr,
    const float2* __restrict__ pairs,
    const float* __restrict__ W, const float* __restrict__ bias,
    const float* __restrict__ bg, const float* __restrict__ bb,
    const float* __restrict__ brm, const float* __restrict__ brv) {
    __shared__ float wsh_t[HDIM * WT_STRIDE];
    __shared__ float sM[HDIM], sC[HDIM];
    int tid = threadIdx.x;
    for (int i = tid; i < HDIM * HDIM; i += 256)
        wsh_t[(i & 63) * WT_STRIDE + (i >> 6)] = W[i];
    if (tid < HDIM) {
        float sc = bg[tid] * rsqrtf(brv[tid] + BN_EPS);
        sM[tid] = sc;
        sC[tid] = (bias[tid] - brm[tid]) * sc + bb[tid];
    }
    __syncthreads();

    int lane = tid & 63;
    int o = lane >> 3, s = lane & 7;
    int f = lane;
    const half8* __restrict__ xin8 = (const half8*)xin;

    int v0 = (blockIdx.x * 4 + (tid >> 6)) * NPW;
    for (int n = 0; n < NPW; n++) {
        int v = v0 + n;
        if (v >= N_NODES) break;
        int e0 = ptr_pad[v], pe1 = ptr_pad[v + 1];
        float acc[8];
        {
            half8 r = xin8[(size_t)v * 8 + s];     // self-loop row (broadcast load)
            float cf = (o == 0) ? 1.f : 0.f;
#pragma unroll
            for (int i = 0; i < 8; i++) acc[i] = cf * (float)r[i];
        }
        for (int e = e0; e < pe1; e += 32) {
            int bb = e + o * 4;
            if (bb < pe1) {
                int4 u4 = *(const int4*)(csr + bb);
                int uu[4] = {u4.x, u4.y, u4.z, u4.w};
#pragma unroll
                for (int c = 0; c < 4; c++) {
                    half8 r = xin8[(size_t)uu[c] * 8 + s]; // 16B/lane; sentinel row = 0
#pragma unroll
                    for (int i = 0; i < 8; i++) acc[i] += (float)r[i];
                }
            }
        }
#pragma unroll
        for (int i = 0; i < 8; i++) {
            acc[i] += __shfl_xor(acc[i], 8);
            acc[i] += __shfl_xor(acc[i], 16);
            acc[i] += __shfl_xor(acc[i], 32);
        }
        const float4* wt4 = (const float4*)&wsh_t[f * WT_STRIDE];
        float ov = 0.f;
#pragma unroll
        for (int k4 = 0; k4 < 16; k4++) {
            float4 w4 = wt4[k4];
            float wc[4] = {w4.x, w4.y, w4.z, w4.w};
#pragma unroll
            for (int j = 0; j < 4; j++) {
                int k = k4 * 4 + j;
                ov += __shfl(acc[k & 7], k >> 3) * wc[j];
            }
        }
        float dv = pairs[v].y;
        float val = fmaxf(dv * ov * sM[f] + sC[f], 0.f);
        xout[(size_t)v * HDIM + f] = (f16)val;
    }
}

// ======== Pool (mean/max per graph) + MLP head ========

__device__ inline int lower_bound_i(const int* __restrict__ a, int n, int val) {
    int lo = 0, hi = n;
    while (lo < hi) {
        int mid = (lo + hi) >> 1;
        if (a[mid] < val) lo = mid + 1; else hi = mid;
    }
    return lo;
}

__global__ void pool_mlp_k(const f16* __restrict__ x, const int* __restrict__ batch,
                           const float* __restrict__ wl1, const float* __restrict__ bl1,
                           const float* __restrict__ wl2, const float* __restrict__ bl2,
                           const float* __restrict__ bg, const float* __restrict__ bb,
                           const float* __restrict__ brm, const float* __restrict__ brv,
                           float* __restrict__ out) {
    int g = blockIdx.x;
    int tid = threadIdx.x;
    int w = tid >> 6;
    int f = tid & 63;
    int start = lower_bound_i(batch, N_NODES, g);
    int end = lower_bound_i(batch, N_NODES, g + 1);
    float sum = 0.f;
    float mx = -3.402823466e38f;
#pragma unroll 2
    for (int v = start + w; v < end; v += 4) {
        float val = (float)x[(size_t)v * HDIM + f];
        sum += val;
        mx = fmaxf(mx, val);
    }
    __shared__ float ssum[4][HDIM], smax[4][HDIM];
    __shared__ float zs[2 * HDIM];
    ssum[w][f] = sum;
    smax[w][f] = mx;
    __syncthreads();
    if (tid < 64) {
        float sm = ssum[0][f] + ssum[1][f] + ssum[2][f] + ssum[3][f];
        float m = fmaxf(fmaxf(smax[0][f], smax[1][f]), fmaxf(smax[2][f], smax[3][f]));
        float cnt = (float)(end - start);
        zs[f] = sm / fmaxf(cnt, 1.f);
        zs[HDIM + f] = m;
    }
    __syncthreads();
    if (tid >= 64) return;

    float o = bl1[f];
#pragma unroll 8
    for (int k = 0; k < 2 * HDIM; k++) {
        o += zs[k] * wl1[k * HDIM + f];
    }
    float sc = bg[f] * rsqrtf(brv[f] + BN_EPS);
    o = fmaxf((o - brm[f]) * sc + bb[f], 0.f);

    float p0 = o * wl2[f * 2 + 0];
    float p1 = o * wl2[f * 2 + 1];
    for (int off = 32; off > 0; off >>= 1) {
        p0 += __shfl_down(p0, off);
        p1 += __shfl_down(p1, off);
    }
    if (f == 0) {
        out[g * 2 + 0] = p0 + bl2[0];
        out[g * 2 + 1] = p1 + bl2[1];
    }
}

// ======== launch ========

extern "C" void kernel_launch(void* const* d_in, const int* in_sizes, int n_in,
                              void* d_out, int out_size, void* d_ws, size_t ws_size,
                              hipStream_t stream) {
    const float* x    = (const float*)d_in[0];
    const int* src    = (const int*)d_in[1];
    const int* dst    = (const int*)d_in[2];
    const int* batch  = (const int*)d_in[3];
    const float* w1   = (const float*)d_in[4];
    const float* b1   = (const float*)d_in[5];
    const float* w2   = (const float*)d_in[6];
    const float* b2   = (const float*)d_in[7];
    const float* w3   = (const float*)d_in[8];
    const float* b3   = (const float*)d_in[9];
    const float* wl1  = (const float*)d_in[10];
    const float* bl1  = (const float*)d_in[11];
    const float* wl2  = (const float*)d_in[12];
    const float* bl2  = (const float*)d_in[13];
    const float* bn1g = (const float*)d_in[14];
    const float* bn1b = (const float*)d_in[15];
    const float* bn1rm = (const float*)d_in[16];
    const float* bn1rv = (const float*)d_in[17];
    const float* bn2g = (const float*)d_in[18];
    const float* bn2b = (const float*)d_in[19];
    const float* bn2rm = (const float*)d_in[20];
    const float* bn2rv = (const float*)d_in[21];
    const float* bn3g = (const float*)d_in[22];
    const float* bn3b = (const float*)d_in[23];
    const float* bn3rm = (const float*)d_in[24];
    const float* bn3rv = (const float*)d_in[25];
    const float* bnlg = (const float*)d_in[26];
    const float* bnlb = (const float*)d_in[27];
    const float* bnlrm = (const float*)d_in[28];
    const float* bnlrv = (const float*)d_in[29];
    float* out = (float*)d_out;

    char* ws = (char*)d_ws;
    size_t off = 0;
    auto alloc = [&](size_t bytes) -> char* {
        off = (off + 255) & ~(size_t)255;
        char* p = ws + off;
        off += bytes;
        return p;
    };
    int*    histT    = (int*)alloc((size_t)NBUCKET * NCHUNK * 4);
    int*    scannedT = (int*)alloc((size_t)NBUCKET * NCHUNK * 4);
    int*    bbase    = (int*)alloc((NBUCKET + 1) * 4);
    int*    pbt      = (int*)alloc(NBUCKET * 4);
    int*    pbbase   = (int*)alloc((NBUCKET + 1) * 4);
    int*    staging  = (int*)alloc((size_t)E_EDGES * 4);
    int*    csr      = (int*)alloc(((size_t)E_EDGES + 4 * N_NODES + 64) * 4);
    int*    ptr_raw  = (int*)alloc(((size_t)N_NODES + 1) * 4);
    int*    ptr_pad  = (int*)alloc(((size_t)N_NODES + 1) * 4);
    float*  dinv     = (float*)alloc((size_t)N_NODES * 4);
    float*  xtil     = (float*)alloc((size_t)N_NODES * 4);
    float2* pairs    = (float2*)alloc(((size_t)N_NODES + 1) * 8);
    float2* m1c1     = (float2*)alloc((size_t)HDIM * 8);
    f16*    x2       = (f16*)alloc(((size_t)N_NODES + 1) * HDIM * 2);
    f16*    x3       = (f16*)alloc((size_t)N_NODES * HDIM * 2);
    if (off > ws_size) {
        fprintf(stderr, "kernel_launch: ws too small (%zu > %zu)\n", off, ws_size);
    }

    const int NB_AGG = (N_NODES + 4 * NPW - 1) / (4 * NPW);  // 3125

    hist_k<<<NCHUNK, 256, 0, stream>>>(dst, histT);
    scanA_k<<<1, 512, 0, stream>>>(histT, bbase, w1, b1, bn1g, bn1b, bn1rm, bn1rv, m1c1);
    scanB_k<<<NBUCKET, NCHUNK, 0, stream>>>(histT, bbase, scannedT);
    scatter_k<<<NCHUNK, 256, 0, stream>>>(src, dst, scannedT, staging);
    nodeptr_k<<<NBUCKET, 256, 0, stream>>>(staging, bbase, x, ptr_raw, dinv, xtil, pbt);
    scanC_k<<<1, 512, 0, stream>>>(pbt, pbbase, ptr_pad);
    csr_l1_k<<<NBUCKET, 256, 0, stream>>>(staging, ptr_raw, bbase, pbbase,
                                          dinv, xtil, x, csr, ptr_pad, pairs);

    agg_l2_k<<<NB_AGG, 256, 0, stream>>>(pairs, m1c1, x2, ptr_pad, csr,
                                         w2, b2, bn2g, bn2b, bn2rm, bn2rv);
    agg_gemm_k<<<NB_AGG, 256, 0, stream>>>(x2, x3, ptr_pad, csr, pairs,
                                           w3, b3, bn3g, bn3b, bn3rm, bn3rv);

    pool_mlp_k<<<N_GRAPH, 256, 0, stream>>>(x3, batch, wl1, bl1, wl2, bl2,
                                            bnlg, bnlb, bnlrm, bnlrv, out);
}